// Round 12
// baseline (563.087 us; speedup 1.0000x reference)
//
#include <hip/hip_runtime.h>
#include <hip/hip_bf16.h>

// Problem constants
#define M_DIM 16384   // 8*2048
#define N_DIM 4096    // OUT_FEATURES
#define K_DIM 4096    // IN_FEATURES

typedef __attribute__((ext_vector_type(8))) short short8_t;
typedef __attribute__((ext_vector_type(4))) float float4_t;
typedef __attribute__((ext_vector_type(4))) int int4_t;

__device__ __forceinline__ short f2bf(float f) {
    union { __hip_bfloat16 b; short s; } u;
    u.b = __float2bfloat16(f);
    return u.s;
}

// ---------------------------------------------------------------------------
// Kernel 1: x f32 -> bf16 (vectorized 8/thread). NT loads (x is read-once).
// ---------------------------------------------------------------------------
__global__ __launch_bounds__(256) void conv_x(const float* __restrict__ x,
                                              short* __restrict__ xb) {
    size_t t = (size_t)blockIdx.x * 256 + threadIdx.x;  // 8,388,608 threads
    const float4_t a = __builtin_nontemporal_load((const float4_t*)(x + t * 8));
    const float4_t b = __builtin_nontemporal_load((const float4_t*)(x + t * 8 + 4));
    short8_t v;
    v[0] = f2bf(a[0]); v[1] = f2bf(a[1]); v[2] = f2bf(a[2]); v[3] = f2bf(a[3]);
    v[4] = f2bf(b[0]); v[5] = f2bf(b[1]); v[6] = f2bf(b[2]); v[7] = f2bf(b[3]);
    *(short8_t*)(xb + t * 8) = v;
}

// ---------------------------------------------------------------------------
// Kernel 2: dequantize packed 4-bit weights -> bf16 [N][K] (K-major).
// ---------------------------------------------------------------------------
__global__ __launch_bounds__(256) void dequant_w(const int* __restrict__ wd,
                                                 const float* __restrict__ scale,
                                                 const float* __restrict__ lut,
                                                 short* __restrict__ Wq) {
    int t = blockIdx.x * 256 + threadIdx.x;       // 2,097,152 threads total
    int row = t >> 9;                             // 512 threads per row
    int cb  = t & 511;                            // 4-byte chunk index within row
    const int4_t w4 = __builtin_nontemporal_load(
        (const int4_t*)&wd[(size_t)row * 2048 + cb * 4]);
    const float s = scale[row * 32 + (cb >> 4)];  // group = (8*cb)/128 = cb/16
    int idx[4] = {w4[0], w4[1], w4[2], w4[3]};
    short8_t v;
#pragma unroll
    for (int j = 0; j < 4; ++j) {
        v[2 * j + 0] = f2bf(lut[idx[j] * 2 + 0] * s);
        v[2 * j + 1] = f2bf(lut[idx[j] * 2 + 1] * s);
    }
    *(short8_t*)&Wq[(size_t)row * K_DIM + cb * 8] = v;
}

// ---------------------------------------------------------------------------
// Kernel 3: 256x256 8-phase bf16 GEMM. Staging/VM schedule = r5 VERIFIED
// (byte-identical). r12: read-ahead with ALL reads in barrier-safe windows.
// Every fragment read is a PRE-read at phase start — i.e. AFTER the previous
// phase-end barrier, which orders EVERY wave's VM waits before it (this fixes
// r11's cross-wave race: r11's POST reads ran before the end barrier).
//   ph1 PRE: afr0+bfr0 (own operands) | SBAR(0) | bfr1   -> lgkm(4)
//   ph2 PRE: afr1                                        -> lgkm(8)
//   ph3 PRE: bfr0 (re-read, region unchanged)            -> lgkm(4)
//   ph4 PRE: none                                        -> lgkm(0), VM4
//   ph5..ph8: mirror on buf1.
// Wait proofs (DS in-order; issue order pinned by sched_barrier):
//   ph1 lgkm(4): 16 issued this phase, leave bfr1's 4 -> afr0,bfr0 done.
//   ph2 lgkm(8): <=12 out (bfr1 4 + afr1 8), leave 8 -> bfr1 done.
//   ph3 lgkm(4): <=12 out (afr1 8 + bfr0 4), leave 4 -> afr1 done.
//   ph4 lgkm(0): drain bfr0.
// Region safety: every PRE region was staged >=2 phases back and drained by
// the prior VM4 (per-wave) + phase-end barrier (cross-wave). LDS WARs
// (ph3-stage A0b0 vs ph2-read afr1; ph4-stage B1b0 vs ph3-read bfr0; ph7/ph8
// mirrors) have one MORE barrier of separation than r5's proven pattern.
// ---------------------------------------------------------------------------
#define LOADA_TO(DST, MH, BUF) \
  _Pragma("unroll") for (int q = 0; q < 4; ++q) { \
    DST[q][0] = *(const short8_t*)(smem + ABASE + (BUF) + ((MH)*4+q)*1024); \
    DST[q][1] = *(const short8_t*)(smem + ABASE + (BUF) + 8192 + ((MH)*4+q)*1024); }

#define LOADB_TO(DST, NH, BUF) \
  _Pragma("unroll") for (int q = 0; q < 2; ++q) { \
    DST[q][0] = *(const short8_t*)(smem + BBASE + (BUF) + ((NH)*2+q)*1024); \
    DST[q][1] = *(const short8_t*)(smem + BBASE + (BUF) + 8192 + ((NH)*2+q)*1024); }

// ph1/ph5 operand+prefetch group: own operands first, order pinned, then bfr1
#define PRE1(BUF) \
  LOADA_TO(afr0, 0, BUF) \
  LOADB_TO(bfr0, 0, BUF) \
  __builtin_amdgcn_sched_barrier(0); \
  LOADB_TO(bfr1, 1, BUF)

#define MFMAQ(MH, NH, AF, BF) \
  _Pragma("unroll") for (int q = 0; q < 4; ++q) \
  _Pragma("unroll") for (int p = 0; p < 2; ++p) { \
    acc[(MH)*4+q][(NH)*2+p] = __builtin_amdgcn_mfma_f32_16x16x32_bf16(AF[q][0], BF[p][0], acc[(MH)*4+q][(NH)*2+p], 0, 0, 0); \
    acc[(MH)*4+q][(NH)*2+p] = __builtin_amdgcn_mfma_f32_16x16x32_bf16(AF[q][1], BF[p][1], acc[(MH)*4+q][(NH)*2+p], 0, 0, 0); }

#define STAGE_F(P, GOFF, DOFF) \
  __builtin_amdgcn_global_load_lds((const __attribute__((address_space(1))) void*)((P) + (GOFF)), \
      (__attribute__((address_space(3))) void*)(smem + (DOFF) + f0), 16, 0, 0); \
  __builtin_amdgcn_global_load_lds((const __attribute__((address_space(1))) void*)((P) + (GOFF) + 64), \
      (__attribute__((address_space(3))) void*)(smem + (DOFF) + 8192 + f0), 16, 0, 0);

#define VM4 asm volatile("s_waitcnt vmcnt(4)" ::: "memory");
#define VM0 asm volatile("s_waitcnt vmcnt(0)" ::: "memory");

#define PHY(PRE, STG, LG, MH, NH, AF, BF, WAITV) \
    PRE \
    STG \
    __builtin_amdgcn_s_barrier(); \
    asm volatile("s_waitcnt lgkmcnt(" LG ")" ::: "memory"); \
    __builtin_amdgcn_sched_barrier(0); \
    __builtin_amdgcn_s_setprio(1); \
    MFMAQ(MH, NH, AF, BF); \
    __builtin_amdgcn_s_setprio(0); \
    WAITV \
    __builtin_amdgcn_s_barrier();

// DOFF: A0b0=0  A1b0=16384  A0b1=32768  A1b1=49152
//       B0b0=65536  B1b0=81920  B0b1=98304  B1b1=114688

__global__ __launch_bounds__(512, 2) void gemm8(const short* __restrict__ A,
                                                const short* __restrict__ B,
                                                float* __restrict__ C) {
    __shared__ __align__(16) char smem[131072];
    const int tid = threadIdx.x;
    const int lane = tid & 63;
    const int wid = tid >> 6;
    const int wr = wid >> 2, wc = wid & 3;
    const int lr = lane & 15;
    const int lk2 = ((lane >> 4) << 3) * 2;          // frag col byte {0,16,32,48}
    const int swz5 = ((lr >> 3) & 1) << 5;

    // T1: XCD-chunked swizzle, bm-fastest within chunk (r9-verified:
    // FETCH 590->393 MB). Resident set: 8 bm x 4 bn per XCD.
    const int xcd = blockIdx.x & 7;
    const int p   = blockIdx.x >> 3;                 // 0..127 within chunk
    const int bm  = xcd * 8 + (p & 7);
    const int bn  = p >> 3;

    // lane-constant LDS read bases (byte offsets); swizzle folded in
    const int ABASE = wr * 16384 + lr * 64 + (lk2 ^ swz5);
    const int BBASE = 65536 + (wc >> 1) * 16384 + (wc & 1) * 4096 + lr * 64 + (lk2 ^ swz5);

    // staging per-thread constants
    const int f0 = tid * 16;                          // LDS byte slot (linear dst)
    const int rr0 = tid >> 2;                         // staged row 0..127
    const int cs0 = (f0 & 63) ^ (((f0 >> 9) & 1) << 5);  // inverse-swz src col byte

    // persistent src pointers at K-tile 2t (advance 256 B/iter)
    const char* pA0 = (const char*)A + ((size_t)(bm * 256 + rr0) * K_DIM) * 2 + cs0;
    const char* pA1 = pA0 + (size_t)128 * K_DIM * 2;
    const char* pB0 = (const char*)B + ((size_t)(bn * 256 + rr0) * K_DIM) * 2 + cs0;
    const char* pB1 = pB0 + (size_t)128 * K_DIM * 2;

    float4_t acc[8][4] = {};
    short8_t afr0[4][2], afr1[4][2];   // A fragment sets (MH quadrants)
    short8_t bfr0[2][2], bfr1[2][2];   // B fragment sets (NH quadrants)

    // prologue: kt0 {A0,B1,A1,B0} -> buf0, kt1 {A0,B1,A1,B0} -> buf1
    STAGE_F(pA0, 0,   0)
    STAGE_F(pB1, 0,   81920)
    STAGE_F(pA1, 0,   16384)
    STAGE_F(pB0, 0,   65536)
    STAGE_F(pA0, 128, 32768)
    STAGE_F(pB1, 128, 114688)
    STAGE_F(pA1, 128, 49152)
    STAGE_F(pB0, 128, 98304)
    asm volatile("s_waitcnt vmcnt(8)" ::: "memory");  // kt0 (buf0) landed
    __builtin_amdgcn_s_barrier();

    // iteration 0 (peeled staging: kt1 already staged; stages start ph3)
    PHY(PRE1(0),                 ,                       "4", 0,0, afr0,bfr0, )
    PHY(LOADA_TO(afr1,1,0),      ,                       "8", 0,1, afr0,bfr1, )
    PHY(LOADB_TO(bfr0,0,0),      STAGE_F(pA0,256,0),     "4", 1,1, afr1,bfr1, )
    PHY(,                        STAGE_F(pB1,256,81920), "0", 1,0, afr1,bfr0, VM4)
    PHY(PRE1(32768),             STAGE_F(pA1,256,16384), "4", 0,0, afr0,bfr0, )
    PHY(LOADA_TO(afr1,1,32768),  STAGE_F(pB0,256,65536), "8", 0,1, afr0,bfr1, )
    PHY(LOADB_TO(bfr0,0,32768),  STAGE_F(pA0,384,32768), "4", 1,1, afr1,bfr1, )
    PHY(,                        STAGE_F(pB1,384,114688),"0", 1,0, afr1,bfr0, VM4)
    pA0 += 256; pA1 += 256; pB0 += 256; pB1 += 256;

#pragma unroll 1
    for (int t = 1; t < 31; ++t) {
        // K-tile 2t from buf0 (stage slots = r5 verified)
        PHY(PRE1(0),                 STAGE_F(pA1,128,49152),  "4", 0,0, afr0,bfr0, )
        PHY(LOADA_TO(afr1,1,0),      STAGE_F(pB0,128,98304),  "8", 0,1, afr0,bfr1, )
        PHY(LOADB_TO(bfr0,0,0),      STAGE_F(pA0,256,0),      "4", 1,1, afr1,bfr1, )
        PHY(,                        STAGE_F(pB1,256,81920),  "0", 1,0, afr1,bfr0, VM4)
        // K-tile 2t+1 from buf1
        PHY(PRE1(32768),             STAGE_F(pA1,256,16384),  "4", 0,0, afr0,bfr0, )
        PHY(LOADA_TO(afr1,1,32768),  STAGE_F(pB0,256,65536),  "8", 0,1, afr0,bfr1, )
        PHY(LOADB_TO(bfr0,0,32768),  STAGE_F(pA0,384,32768),  "4", 1,1, afr1,bfr1, )
        PHY(,                        STAGE_F(pB1,384,114688), "0", 1,0, afr1,bfr0, VM4)
        pA0 += 256; pA1 += 256; pB0 += 256; pB1 += 256;
    }

    // tail t=31 (kt62 b0, kt63 b1): only kt63 A1(ph1)/B0(ph2) left to stage
    PHY(PRE1(0),                 STAGE_F(pA1,128,49152), "4", 0,0, afr0,bfr0, )
    PHY(LOADA_TO(afr1,1,0),      STAGE_F(pB0,128,98304), "8", 0,1, afr0,bfr1, )
    PHY(LOADB_TO(bfr0,0,0),      ,                       "4", 1,1, afr1,bfr1, )
    PHY(,                        ,                       "0", 1,0, afr1,bfr0, VM0)
    PHY(PRE1(32768),             , "4", 0,0, afr0,bfr0, )
    PHY(LOADA_TO(afr1,1,32768),  , "8", 0,1, afr0,bfr1, )
    PHY(LOADB_TO(bfr0,0,32768),  , "4", 1,1, afr1,bfr1, )
    PHY(,                        , "0", 1,0, afr1,bfr0, )

    // Epilogue: D mapping col = lane&15, row = (lane>>4)*4 + r (m89-verified)
    const int orow0 = bm * 256 + wr * 128;
    const int ocol0 = bn * 256 + wc * 64 + lr;
    const int rsub = (lane >> 4) << 2;
#pragma unroll
    for (int mi = 0; mi < 8; ++mi) {
#pragma unroll
        for (int r = 0; r < 4; ++r) {
            int row = orow0 + mi * 16 + rsub + r;
            float* cp = C + (size_t)row * N_DIM + ocol0;
#pragma unroll
            for (int ni = 0; ni < 4; ++ni)
                cp[ni * 16] = acc[mi][ni][r];
        }
    }
}

// ---------------------------------------------------------------------------
// Fallback GEMM (fp32 A staged with conversion) — only if workspace too small.
// ---------------------------------------------------------------------------
__global__ __launch_bounds__(256) void gemm_fb(const float* __restrict__ A,
                                               const short* __restrict__ B,
                                               float* __restrict__ C) {
    __shared__ short Al[128 * 32];
    __shared__ short Bl[128 * 32];
    const int bid0 = blockIdx.x;
    const int bid = (bid0 & 7) * 512 + (bid0 >> 3);
    const int bm = bid >> 5, bn = bid & 31;
    const int tid = threadIdx.x;
    const int lane = tid & 63;
    const int w = tid >> 6;
    const int wr = w >> 1, wc = w & 1;
    const int lr = lane & 15;
    const int lk = (lane >> 4) << 3;
    float4_t acc[4][4] = {};
    for (int k0 = 0; k0 < K_DIM; k0 += 32) {
        __syncthreads();
#pragma unroll
        for (int i = 0; i < 2; ++i) {
            int e = i * 2048 + tid * 8;
            int row = e >> 5, col = e & 31;
            const float* gp = A + (size_t)(bm * 128 + row) * K_DIM + k0 + col;
            float4 fa = *(const float4*)gp;
            float4 fb = *(const float4*)(gp + 4);
            short8_t v;
            v[0] = f2bf(fa.x); v[1] = f2bf(fa.y); v[2] = f2bf(fa.z); v[3] = f2bf(fa.w);
            v[4] = f2bf(fb.x); v[5] = f2bf(fb.y); v[6] = f2bf(fb.z); v[7] = f2bf(fb.w);
            *(short8_t*)&Al[e] = v;
        }
#pragma unroll
        for (int i = 0; i < 2; ++i) {
            int f = i * 4096 + tid * 16;
            int row = f >> 6, colb = f & 63;
            const char* gb = (const char*)B + ((size_t)(bn * 128 + row) * K_DIM + k0) * 2 + colb;
            __builtin_amdgcn_global_load_lds(
                (const __attribute__((address_space(1))) void*)gb,
                (__attribute__((address_space(3))) void*)((char*)Bl + f), 16, 0, 0);
        }
        __syncthreads();
        short8_t af[4], bf[4];
#pragma unroll
        for (int mi = 0; mi < 4; ++mi)
            af[mi] = *(const short8_t*)&Al[(wr * 64 + mi * 16 + lr) * 32 + lk];
#pragma unroll
        for (int ni = 0; ni < 4; ++ni)
            bf[ni] = *(const short8_t*)&Bl[(wc * 64 + ni * 16 + lr) * 32 + lk];
#pragma unroll
        for (int mi = 0; mi < 4; ++mi)
#pragma unroll
            for (int ni = 0; ni < 4; ++ni)
                acc[mi][ni] = __builtin_amdgcn_mfma_f32_16x16x32_bf16(af[mi], bf[ni], acc[mi][ni], 0, 0, 0);
    }
    const int orow0 = bm * 128 + wr * 64;
    const int ocol0 = bn * 128 + wc * 64 + (lane & 15);
#pragma unroll
    for (int mi = 0; mi < 4; ++mi)
#pragma unroll
        for (int r = 0; r < 4; ++r) {
            int row = orow0 + mi * 16 + ((lane >> 4) << 2) + r;
            float* cp = C + (size_t)row * N_DIM + ocol0;
#pragma unroll
            for (int ni = 0; ni < 4; ++ni)
                cp[ni * 16] = acc[mi][ni][r];
        }
}

// ---------------------------------------------------------------------------
extern "C" void kernel_launch(void* const* d_in, const int* in_sizes, int n_in,
                              void* d_out, int out_size, void* d_ws, size_t ws_size,
                              hipStream_t stream) {
    const float* x     = (const float*)d_in[0];
    const int*   wd    = (const int*)d_in[1];
    const float* scale = (const float*)d_in[2];
    const float* lut   = (const float*)d_in[3];
    float* out = (float*)d_out;

    const size_t wq_bytes = (size_t)N_DIM * K_DIM * 2;   // 32 MB
    const size_t xb_bytes = (size_t)M_DIM * K_DIM * 2;   // 128 MB
    short* Wq = (short*)d_ws;
    short* xb = (short*)((char*)d_ws + wq_bytes);
    const bool have_xb = ws_size >= wq_bytes + xb_bytes;

    if (have_xb) {
        conv_x<<<32768, 256, 0, stream>>>(x, xb);
        dequant_w<<<8192, 256, 0, stream>>>(wd, scale, lut, Wq);
        gemm8<<<(M_DIM / 256) * (N_DIM / 256), 512, 0, stream>>>(xb, Wq, out);
    } else {
        dequant_w<<<8192, 256, 0, stream>>>(wd, scale, lut, Wq);
        gemm_fb<<<(M_DIM / 128) * (N_DIM / 128), 256, 0, stream>>>(x, Wq, out);
    }
}

// Round 14
// 557.956 us; speedup vs baseline: 1.0092x; 1.0092x over previous
//
#include <hip/hip_runtime.h>
#include <hip/hip_bf16.h>

// Problem constants
#define M_DIM 16384   // 8*2048
#define N_DIM 4096    // OUT_FEATURES
#define K_DIM 4096    // IN_FEATURES

typedef __attribute__((ext_vector_type(8))) short short8_t;
typedef __attribute__((ext_vector_type(4))) float float4_t;

__device__ __forceinline__ short f2bf(float f) {
    union { __hip_bfloat16 b; short s; } u;
    u.b = __float2bfloat16(f);
    return u.s;
}

// ---------------------------------------------------------------------------
// Kernel 1: dequantize packed 4-bit weights -> bf16 [N][K] (K-major)
// ---------------------------------------------------------------------------
__global__ __launch_bounds__(256) void dequant_w(const int* __restrict__ wd,
                                                 const float* __restrict__ scale,
                                                 const float* __restrict__ lut,
                                                 short* __restrict__ Wq) {
    int t = blockIdx.x * 256 + threadIdx.x;       // 2,097,152 threads total
    int row = t >> 9;                             // 512 threads per row
    int cb  = t & 511;                            // 4-byte chunk index within row
    const int4 w4 = *(const int4*)&wd[(size_t)row * 2048 + cb * 4];
    const float s = scale[row * 32 + (cb >> 4)];  // group = (8*cb)/128 = cb/16
    int idx[4] = {w4.x, w4.y, w4.z, w4.w};
    short8_t v;
#pragma unroll
    for (int j = 0; j < 4; ++j) {
        v[2 * j + 0] = f2bf(lut[idx[j] * 2 + 0] * s);
        v[2 * j + 1] = f2bf(lut[idx[j] * 2 + 1] * s);
    }
    *(short8_t*)&Wq[(size_t)row * K_DIM + cb * 8] = v;
}

// ---------------------------------------------------------------------------
// Kernel 2: x f32 -> bf16 (vectorized 8/thread)
// ---------------------------------------------------------------------------
__global__ __launch_bounds__(256) void conv_x(const float* __restrict__ x,
                                              short* __restrict__ xb) {
    size_t t = (size_t)blockIdx.x * 256 + threadIdx.x;  // 8,388,608 threads
    const float4 a = *(const float4*)(x + t * 8);
    const float4 b = *(const float4*)(x + t * 8 + 4);
    short8_t v;
    v[0] = f2bf(a.x); v[1] = f2bf(a.y); v[2] = f2bf(a.z); v[3] = f2bf(a.w);
    v[4] = f2bf(b.x); v[5] = f2bf(b.y); v[6] = f2bf(b.z); v[7] = f2bf(b.w);
    *(short8_t*)(xb + t * 8) = v;
}

// ---------------------------------------------------------------------------
// Kernel 3: 256x256 8-phase bf16 GEMM (T1+T2+T3+T4+T5), hoisted staging.
//   K-loop schedule = round-5 VERIFIED (505us, MfmaUtil 51, conflicts 0).
//   bm-fastest XCD swizzle (r9-verified: FETCH 590->393 MB).
//   Staging: slot s at phase s-5; VM4 at ph4/ph8 (provably minimal/safe).
//   NOTE (r13 post-mortem): 2 blocks/CU is infeasible — acc[8][4] f32x4
//   = 128 VGPR alone = the entire 4-wave/SIMD budget; forcing it spills
//   to scratch, and scratch ops count in vmcnt -> breaks counted waits.
// ---------------------------------------------------------------------------
#define LOADA(MH, BUF) \
  _Pragma("unroll") for (int q = 0; q < 4; ++q) { \
    afr[q][0] = *(const short8_t*)(smem + ABASE + (BUF) + ((MH)*4+q)*1024); \
    afr[q][1] = *(const short8_t*)(smem + ABASE + (BUF) + 8192 + ((MH)*4+q)*1024); }

#define LOADB(NH, BUF) \
  _Pragma("unroll") for (int q = 0; q < 2; ++q) { \
    bfr[q][0] = *(const short8_t*)(smem + BBASE + (BUF) + ((NH)*2+q)*1024); \
    bfr[q][1] = *(const short8_t*)(smem + BBASE + (BUF) + 8192 + ((NH)*2+q)*1024); }

#define MFMAQ(MH, NH) \
  _Pragma("unroll") for (int q = 0; q < 4; ++q) \
  _Pragma("unroll") for (int p = 0; p < 2; ++p) { \
    acc[(MH)*4+q][(NH)*2+p] = __builtin_amdgcn_mfma_f32_16x16x32_bf16(afr[q][0], bfr[p][0], acc[(MH)*4+q][(NH)*2+p], 0, 0, 0); \
    acc[(MH)*4+q][(NH)*2+p] = __builtin_amdgcn_mfma_f32_16x16x32_bf16(afr[q][1], bfr[p][1], acc[(MH)*4+q][(NH)*2+p], 0, 0, 0); }

#define STAGE_F(P, GOFF, DOFF) \
  __builtin_amdgcn_global_load_lds((const __attribute__((address_space(1))) void*)((P) + (GOFF)), \
      (__attribute__((address_space(3))) void*)(smem + (DOFF) + f0), 16, 0, 0); \
  __builtin_amdgcn_global_load_lds((const __attribute__((address_space(1))) void*)((P) + (GOFF) + 64), \
      (__attribute__((address_space(3))) void*)(smem + (DOFF) + 8192 + f0), 16, 0, 0);

#define VM4 asm volatile("s_waitcnt vmcnt(4)" ::: "memory");
#define VM0 asm volatile("s_waitcnt vmcnt(0)" ::: "memory");

#define PH2(LOADS, MH, NH, STG, WAITV) \
    LOADS \
    STG \
    __builtin_amdgcn_s_barrier(); \
    asm volatile("s_waitcnt lgkmcnt(0)" ::: "memory"); \
    __builtin_amdgcn_s_setprio(1); \
    MFMAQ(MH, NH); \
    __builtin_amdgcn_s_setprio(0); \
    WAITV \
    __builtin_amdgcn_s_barrier();

// DOFF: A0b0=0  A1b0=16384  A0b1=32768  A1b1=49152
//       B0b0=65536  B1b0=81920  B0b1=98304  B1b1=114688

__global__ __launch_bounds__(512, 2) void gemm8(const short* __restrict__ A,
                                                const short* __restrict__ B,
                                                float* __restrict__ C) {
    __shared__ __align__(16) char smem[131072];
    const int tid = threadIdx.x;
    const int lane = tid & 63;
    const int wid = tid >> 6;
    const int wr = wid >> 2, wc = wid & 3;
    const int lr = lane & 15;
    const int lk2 = ((lane >> 4) << 3) * 2;          // frag col byte {0,16,32,48}
    const int swz5 = ((lr >> 3) & 1) << 5;

    // T1: XCD-chunked swizzle, bm-fastest within chunk (r9-verified:
    // FETCH 590->393 MB). Resident set: 8 bm x 4 bn per XCD.
    const int xcd = blockIdx.x & 7;
    const int p   = blockIdx.x >> 3;                 // 0..127 within chunk
    const int bm  = xcd * 8 + (p & 7);
    const int bn  = p >> 3;

    // lane-constant LDS read bases (byte offsets); swizzle folded in
    const int ABASE = wr * 16384 + lr * 64 + (lk2 ^ swz5);
    const int BBASE = 65536 + (wc >> 1) * 16384 + (wc & 1) * 4096 + lr * 64 + (lk2 ^ swz5);

    // staging per-thread constants
    const int f0 = tid * 16;                          // LDS byte slot (linear dst)
    const int rr0 = tid >> 2;                         // staged row 0..127
    const int cs0 = (f0 & 63) ^ (((f0 >> 9) & 1) << 5);  // inverse-swz src col byte

    // persistent src pointers at K-tile 2t (advance 256 B/iter)
    const char* pA0 = (const char*)A + ((size_t)(bm * 256 + rr0) * K_DIM) * 2 + cs0;
    const char* pA1 = pA0 + (size_t)128 * K_DIM * 2;
    const char* pB0 = (const char*)B + ((size_t)(bn * 256 + rr0) * K_DIM) * 2 + cs0;
    const char* pB1 = pB0 + (size_t)128 * K_DIM * 2;

    float4_t acc[8][4] = {};
    short8_t afr[4][2], bfr[2][2];

    // prologue: kt0 {A0,B1,A1,B0} -> buf0, kt1 {A0,B1,A1,B0} -> buf1
    STAGE_F(pA0, 0,   0)
    STAGE_F(pB1, 0,   81920)
    STAGE_F(pA1, 0,   16384)
    STAGE_F(pB0, 0,   65536)
    STAGE_F(pA0, 128, 32768)
    STAGE_F(pB1, 128, 114688)
    STAGE_F(pA1, 128, 49152)
    STAGE_F(pB0, 128, 98304)
    asm volatile("s_waitcnt vmcnt(8)" ::: "memory");  // kt0 (buf0) landed
    __builtin_amdgcn_s_barrier();

    // iteration 0 (peeled): kt1 already fully staged; stages start at ph3
    PH2(LOADA(0,0) LOADB(0,0), 0, 0, , )                                   // ph1
    PH2(LOADB(1,0),            0, 1, , )                                   // ph2
    PH2(LOADA(1,0),            1, 1, STAGE_F(pA0, 256, 0),      )          // ph3
    PH2(LOADB(0,0),            1, 0, STAGE_F(pB1, 256, 81920),  VM4)       // ph4
    PH2(LOADA(0,32768) LOADB(0,32768), 0, 0, STAGE_F(pA1, 256, 16384), )   // ph5
    PH2(LOADB(1,32768),                0, 1, STAGE_F(pB0, 256, 65536), )   // ph6
    PH2(LOADA(1,32768),                1, 1, STAGE_F(pA0, 384, 32768), )   // ph7
    PH2(LOADB(0,32768),                1, 0, STAGE_F(pB1, 384, 114688), VM4) // ph8
    pA0 += 256; pA1 += 256; pB0 += 256; pB1 += 256;

#pragma unroll 1
    for (int t = 1; t < 31; ++t) {
        // K-tile 2t from buf0; stage slot = phase + 5 (round-5 verified order)
        PH2(LOADA(0,0) LOADB(0,0), 0, 0, STAGE_F(pA1, 128, 49152),  )      // ph1: kt+1 A1->b1
        PH2(LOADB(1,0),            0, 1, STAGE_F(pB0, 128, 98304),  )      // ph2: kt+1 B0->b1
        PH2(LOADA(1,0),            1, 1, STAGE_F(pA0, 256, 0),      )      // ph3: kt+2 A0->b0
        PH2(LOADB(0,0),            1, 0, STAGE_F(pB1, 256, 81920),  VM4)   // ph4: kt+2 B1->b0
        // K-tile 2t+1 from buf1
        PH2(LOADA(0,32768) LOADB(0,32768), 0, 0, STAGE_F(pA1, 256, 16384), )   // ph5: kt+2 A1->b0
        PH2(LOADB(1,32768),                0, 1, STAGE_F(pB0, 256, 65536), )   // ph6: kt+2 B0->b0
        PH2(LOADA(1,32768),                1, 1, STAGE_F(pA0, 384, 32768), )   // ph7: kt+3 A0->b1
        PH2(LOADB(0,32768),                1, 0, STAGE_F(pB1, 384, 114688), VM4) // ph8: kt+3 B1->b1
        pA0 += 256; pA1 += 256; pB0 += 256; pB1 += 256;
    }

    // tail iteration t=31: only kt63 A1 (ph1) and B0 (ph2) remain to stage
    PH2(LOADA(0,0) LOADB(0,0), 0, 0, STAGE_F(pA1, 128, 49152), )
    PH2(LOADB(1,0),            0, 1, STAGE_F(pB0, 128, 98304), )
    PH2(LOADA(1,0),            1, 1, , )
    PH2(LOADB(0,0),            1, 0, , VM0)
    PH2(LOADA(0,32768) LOADB(0,32768), 0, 0, , )
    PH2(LOADB(1,32768),                0, 1, , )
    PH2(LOADA(1,32768),                1, 1, , )
    PH2(LOADB(0,32768),                1, 0, , )

    // Epilogue: D mapping col = lane&15, row = (lane>>4)*4 + r (m89-verified)
    const int orow0 = bm * 256 + wr * 128;
    const int ocol0 = bn * 256 + wc * 64 + lr;
    const int rsub = (lane >> 4) << 2;
#pragma unroll
    for (int mi = 0; mi < 8; ++mi) {
#pragma unroll
        for (int r = 0; r < 4; ++r) {
            int row = orow0 + mi * 16 + rsub + r;
            float* cp = C + (size_t)row * N_DIM + ocol0;
#pragma unroll
            for (int ni = 0; ni < 4; ++ni)
                cp[ni * 16] = acc[mi][ni][r];
        }
    }
}

// ---------------------------------------------------------------------------
// Fallback GEMM (fp32 A staged with conversion) — only if workspace too small.
// ---------------------------------------------------------------------------
__global__ __launch_bounds__(256) void gemm_fb(const float* __restrict__ A,
                                               const short* __restrict__ B,
                                               float* __restrict__ C) {
    __shared__ short Al[128 * 32];
    __shared__ short Bl[128 * 32];
    const int bid0 = blockIdx.x;
    const int bid = (bid0 & 7) * 512 + (bid0 >> 3);
    const int bm = bid >> 5, bn = bid & 31;
    const int tid = threadIdx.x;
    const int lane = tid & 63;
    const int w = tid >> 6;
    const int wr = w >> 1, wc = w & 1;
    const int lr = lane & 15;
    const int lk = (lane >> 4) << 3;
    float4_t acc[4][4] = {};
    for (int k0 = 0; k0 < K_DIM; k0 += 32) {
        __syncthreads();
#pragma unroll
        for (int i = 0; i < 2; ++i) {
            int e = i * 2048 + tid * 8;
            int row = e >> 5, col = e & 31;
            const float* gp = A + (size_t)(bm * 128 + row) * K_DIM + k0 + col;
            float4 fa = *(const float4*)gp;
            float4 fb = *(const float4*)(gp + 4);
            short8_t v;
            v[0] = f2bf(fa.x); v[1] = f2bf(fa.y); v[2] = f2bf(fa.z); v[3] = f2bf(fa.w);
            v[4] = f2bf(fb.x); v[5] = f2bf(fb.y); v[6] = f2bf(fb.z); v[7] = f2bf(fb.w);
            *(short8_t*)&Al[e] = v;
        }
#pragma unroll
        for (int i = 0; i < 2; ++i) {
            int f = i * 4096 + tid * 16;
            int row = f >> 6, colb = f & 63;
            const char* gb = (const char*)B + ((size_t)(bn * 128 + row) * K_DIM + k0) * 2 + colb;
            __builtin_amdgcn_global_load_lds(
                (const __attribute__((address_space(1))) void*)gb,
                (__attribute__((address_space(3))) void*)((char*)Bl + f), 16, 0, 0);
        }
        __syncthreads();
        short8_t af[4], bf[4];
#pragma unroll
        for (int mi = 0; mi < 4; ++mi)
            af[mi] = *(const short8_t*)&Al[(wr * 64 + mi * 16 + lr) * 32 + lk];
#pragma unroll
        for (int ni = 0; ni < 4; ++ni)
            bf[ni] = *(const short8_t*)&Bl[(wc * 64 + ni * 16 + lr) * 32 + lk];
#pragma unroll
        for (int mi = 0; mi < 4; ++mi)
#pragma unroll
            for (int ni = 0; ni < 4; ++ni)
                acc[mi][ni] = __builtin_amdgcn_mfma_f32_16x16x32_bf16(af[mi], bf[ni], acc[mi][ni], 0, 0, 0);
    }
    const int orow0 = bm * 128 + wr * 64;
    const int ocol0 = bn * 128 + wc * 64 + (lane & 15);
#pragma unroll
    for (int mi = 0; mi < 4; ++mi)
#pragma unroll
        for (int r = 0; r < 4; ++r) {
            int row = orow0 + mi * 16 + ((lane >> 4) << 2) + r;
            float* cp = C + (size_t)row * N_DIM + ocol0;
#pragma unroll
            for (int ni = 0; ni < 4; ++ni)
                cp[ni * 16] = acc[mi][ni][r];
        }
}

// ---------------------------------------------------------------------------
extern "C" void kernel_launch(void* const* d_in, const int* in_sizes, int n_in,
                              void* d_out, int out_size, void* d_ws, size_t ws_size,
                              hipStream_t stream) {
    const float* x     = (const float*)d_in[0];
    const int*   wd    = (const int*)d_in[1];
    const float* scale = (const float*)d_in[2];
    const float* lut   = (const float*)d_in[3];
    float* out = (float*)d_out;

    const size_t wq_bytes = (size_t)N_DIM * K_DIM * 2;   // 32 MB
    const size_t xb_bytes = (size_t)M_DIM * K_DIM * 2;   // 128 MB
    short* Wq = (short*)d_ws;
    short* xb = (short*)((char*)d_ws + wq_bytes);
    const bool have_xb = ws_size >= wq_bytes + xb_bytes;

    dequant_w<<<8192, 256, 0, stream>>>(wd, scale, lut, Wq);

    if (have_xb) {
        conv_x<<<32768, 256, 0, stream>>>(x, xb);
        gemm8<<<(M_DIM / 256) * (N_DIM / 256), 512, 0, stream>>>(xb, Wq, out);
    } else {
        gemm_fb<<<(M_DIM / 128) * (N_DIM / 128), 256, 0, stream>>>(x, Wq, out);
    }
}

// Round 16
// 556.124 us; speedup vs baseline: 1.0125x; 1.0033x over previous
//
#include <hip/hip_runtime.h>
#include <hip/hip_bf16.h>

// Problem constants
#define M_DIM 16384   // 8*2048
#define N_DIM 4096    // OUT_FEATURES
#define K_DIM 4096    // IN_FEATURES

typedef __attribute__((ext_vector_type(8))) short short8_t;
typedef __attribute__((ext_vector_type(4))) float float4_t;

__device__ __forceinline__ short f2bf(float f) {
    union { __hip_bfloat16 b; short s; } u;
    u.b = __float2bfloat16(f);
    return u.s;
}

// ---------------------------------------------------------------------------
// Kernel 1: dequantize packed 4-bit weights -> bf16 [N][K] (K-major)
// ---------------------------------------------------------------------------
__global__ __launch_bounds__(256) void dequant_w(const int* __restrict__ wd,
                                                 const float* __restrict__ scale,
                                                 const float* __restrict__ lut,
                                                 short* __restrict__ Wq) {
    int t = blockIdx.x * 256 + threadIdx.x;       // 2,097,152 threads total
    int row = t >> 9;                             // 512 threads per row
    int cb  = t & 511;                            // 4-byte chunk index within row
    const int4 w4 = *(const int4*)&wd[(size_t)row * 2048 + cb * 4];
    const float s = scale[row * 32 + (cb >> 4)];  // group = (8*cb)/128 = cb/16
    int idx[4] = {w4.x, w4.y, w4.z, w4.w};
    short8_t v;
#pragma unroll
    for (int j = 0; j < 4; ++j) {
        v[2 * j + 0] = f2bf(lut[idx[j] * 2 + 0] * s);
        v[2 * j + 1] = f2bf(lut[idx[j] * 2 + 1] * s);
    }
    *(short8_t*)&Wq[(size_t)row * K_DIM + cb * 8] = v;
}

// ---------------------------------------------------------------------------
// Kernel 2: x f32 -> bf16 (vectorized 8/thread)
// ---------------------------------------------------------------------------
__global__ __launch_bounds__(256) void conv_x(const float* __restrict__ x,
                                              short* __restrict__ xb) {
    size_t t = (size_t)blockIdx.x * 256 + threadIdx.x;  // 8,388,608 threads
    const float4 a = *(const float4*)(x + t * 8);
    const float4 b = *(const float4*)(x + t * 8 + 4);
    short8_t v;
    v[0] = f2bf(a.x); v[1] = f2bf(a.y); v[2] = f2bf(a.z); v[3] = f2bf(a.w);
    v[4] = f2bf(b.x); v[5] = f2bf(b.y); v[6] = f2bf(b.z); v[7] = f2bf(b.w);
    *(short8_t*)(xb + t * 8) = v;
}

// ---------------------------------------------------------------------------
// Kernel 3: 256x256 8-phase bf16 GEMM (T1+T2+T3+T4+T5), hoisted staging.
//   K-loop schedule = round-5 VERIFIED (505us, MfmaUtil 51, conflicts 0).
//   bm-fastest XCD swizzle (r9-verified: FETCH 590->393 MB).
//   Staging: slot s at phase s-5; VM4 at ph4/ph8 (provably minimal/safe).
//   Per-phase fragment RE-READS are load-bearing: both register-reuse
//   variants (r8, r15) failed with unexplained corruption — do not remove
//   the re-reads without a disasm-level verification loop.
//   NOTE (r13): 2 blocks/CU infeasible — acc alone = 128 VGPR; forcing it
//   spills to scratch, and scratch ops count in vmcnt -> breaks counted waits.
// ---------------------------------------------------------------------------
#define LOADA(MH, BUF) \
  _Pragma("unroll") for (int q = 0; q < 4; ++q) { \
    afr[q][0] = *(const short8_t*)(smem + ABASE + (BUF) + ((MH)*4+q)*1024); \
    afr[q][1] = *(const short8_t*)(smem + ABASE + (BUF) + 8192 + ((MH)*4+q)*1024); }

#define LOADB(NH, BUF) \
  _Pragma("unroll") for (int q = 0; q < 2; ++q) { \
    bfr[q][0] = *(const short8_t*)(smem + BBASE + (BUF) + ((NH)*2+q)*1024); \
    bfr[q][1] = *(const short8_t*)(smem + BBASE + (BUF) + 8192 + ((NH)*2+q)*1024); }

#define MFMAQ(MH, NH) \
  _Pragma("unroll") for (int q = 0; q < 4; ++q) \
  _Pragma("unroll") for (int p = 0; p < 2; ++p) { \
    acc[(MH)*4+q][(NH)*2+p] = __builtin_amdgcn_mfma_f32_16x16x32_bf16(afr[q][0], bfr[p][0], acc[(MH)*4+q][(NH)*2+p], 0, 0, 0); \
    acc[(MH)*4+q][(NH)*2+p] = __builtin_amdgcn_mfma_f32_16x16x32_bf16(afr[q][1], bfr[p][1], acc[(MH)*4+q][(NH)*2+p], 0, 0, 0); }

#define STAGE_F(P, GOFF, DOFF) \
  __builtin_amdgcn_global_load_lds((const __attribute__((address_space(1))) void*)((P) + (GOFF)), \
      (__attribute__((address_space(3))) void*)(smem + (DOFF) + f0), 16, 0, 0); \
  __builtin_amdgcn_global_load_lds((const __attribute__((address_space(1))) void*)((P) + (GOFF) + 64), \
      (__attribute__((address_space(3))) void*)(smem + (DOFF) + 8192 + f0), 16, 0, 0);

#define VM4 asm volatile("s_waitcnt vmcnt(4)" ::: "memory");
#define VM0 asm volatile("s_waitcnt vmcnt(0)" ::: "memory");

#define PH2(LOADS, MH, NH, STG, WAITV) \
    LOADS \
    STG \
    __builtin_amdgcn_s_barrier(); \
    asm volatile("s_waitcnt lgkmcnt(0)" ::: "memory"); \
    __builtin_amdgcn_s_setprio(1); \
    MFMAQ(MH, NH); \
    __builtin_amdgcn_s_setprio(0); \
    WAITV \
    __builtin_amdgcn_s_barrier();

// DOFF: A0b0=0  A1b0=16384  A0b1=32768  A1b1=49152
//       B0b0=65536  B1b0=81920  B0b1=98304  B1b1=114688

__global__ __launch_bounds__(512, 2) void gemm8(const short* __restrict__ A,
                                                const short* __restrict__ B,
                                                float* __restrict__ C) {
    __shared__ __align__(16) char smem[131072];
    const int tid = threadIdx.x;
    const int lane = tid & 63;
    const int wid = tid >> 6;
    const int wr = wid >> 2, wc = wid & 3;
    const int lr = lane & 15;
    const int lk2 = ((lane >> 4) << 3) * 2;          // frag col byte {0,16,32,48}
    const int swz5 = ((lr >> 3) & 1) << 5;

    // T1: XCD-chunked swizzle, bm-fastest within chunk (r9-verified:
    // FETCH 590->393 MB). Resident set: 8 bm x 4 bn per XCD.
    const int xcd = blockIdx.x & 7;
    const int p   = blockIdx.x >> 3;                 // 0..127 within chunk
    const int bm  = xcd * 8 + (p & 7);
    const int bn  = p >> 3;

    // lane-constant LDS read bases (byte offsets); swizzle folded in
    const int ABASE = wr * 16384 + lr * 64 + (lk2 ^ swz5);
    const int BBASE = 65536 + (wc >> 1) * 16384 + (wc & 1) * 4096 + lr * 64 + (lk2 ^ swz5);

    // staging per-thread constants
    const int f0 = tid * 16;                          // LDS byte slot (linear dst)
    const int rr0 = tid >> 2;                         // staged row 0..127
    const int cs0 = (f0 & 63) ^ (((f0 >> 9) & 1) << 5);  // inverse-swz src col byte

    // persistent src pointers at K-tile 2t (advance 256 B/iter)
    const char* pA0 = (const char*)A + ((size_t)(bm * 256 + rr0) * K_DIM) * 2 + cs0;
    const char* pA1 = pA0 + (size_t)128 * K_DIM * 2;
    const char* pB0 = (const char*)B + ((size_t)(bn * 256 + rr0) * K_DIM) * 2 + cs0;
    const char* pB1 = pB0 + (size_t)128 * K_DIM * 2;

    float4_t acc[8][4] = {};
    short8_t afr[4][2], bfr[2][2];

    // prologue: kt0 {A0,B1,A1,B0} -> buf0, kt1 {A0,B1,A1,B0} -> buf1
    STAGE_F(pA0, 0,   0)
    STAGE_F(pB1, 0,   81920)
    STAGE_F(pA1, 0,   16384)
    STAGE_F(pB0, 0,   65536)
    STAGE_F(pA0, 128, 32768)
    STAGE_F(pB1, 128, 114688)
    STAGE_F(pA1, 128, 49152)
    STAGE_F(pB0, 128, 98304)
    asm volatile("s_waitcnt vmcnt(8)" ::: "memory");  // kt0 (buf0) landed
    __builtin_amdgcn_s_barrier();

    // iteration 0 (peeled): kt1 already fully staged; stages start at ph3
    PH2(LOADA(0,0) LOADB(0,0), 0, 0, , )                                   // ph1
    PH2(LOADB(1,0),            0, 1, , )                                   // ph2
    PH2(LOADA(1,0),            1, 1, STAGE_F(pA0, 256, 0),      )          // ph3
    PH2(LOADB(0,0),            1, 0, STAGE_F(pB1, 256, 81920),  VM4)       // ph4
    PH2(LOADA(0,32768) LOADB(0,32768), 0, 0, STAGE_F(pA1, 256, 16384), )   // ph5
    PH2(LOADB(1,32768),                0, 1, STAGE_F(pB0, 256, 65536), )   // ph6
    PH2(LOADA(1,32768),                1, 1, STAGE_F(pA0, 384, 32768), )   // ph7
    PH2(LOADB(0,32768),                1, 0, STAGE_F(pB1, 384, 114688), VM4) // ph8
    pA0 += 256; pA1 += 256; pB0 += 256; pB1 += 256;

#pragma unroll 1
    for (int t = 1; t < 31; ++t) {
        // K-tile 2t from buf0; stage slot = phase + 5 (round-5 verified order)
        PH2(LOADA(0,0) LOADB(0,0), 0, 0, STAGE_F(pA1, 128, 49152),  )      // ph1: kt+1 A1->b1
        PH2(LOADB(1,0),            0, 1, STAGE_F(pB0, 128, 98304),  )      // ph2: kt+1 B0->b1
        PH2(LOADA(1,0),            1, 1, STAGE_F(pA0, 256, 0),      )      // ph3: kt+2 A0->b0
        PH2(LOADB(0,0),            1, 0, STAGE_F(pB1, 256, 81920),  VM4)   // ph4: kt+2 B1->b0
        // K-tile 2t+1 from buf1
        PH2(LOADA(0,32768) LOADB(0,32768), 0, 0, STAGE_F(pA1, 256, 16384), )   // ph5: kt+2 A1->b0
        PH2(LOADB(1,32768),                0, 1, STAGE_F(pB0, 256, 65536), )   // ph6: kt+2 B0->b0
        PH2(LOADA(1,32768),                1, 1, STAGE_F(pA0, 384, 32768), )   // ph7: kt+3 A0->b1
        PH2(LOADB(0,32768),                1, 0, STAGE_F(pB1, 384, 114688), VM4) // ph8: kt+3 B1->b1
        pA0 += 256; pA1 += 256; pB0 += 256; pB1 += 256;
    }

    // tail iteration t=31: only kt63 A1 (ph1) and B0 (ph2) remain to stage
    PH2(LOADA(0,0) LOADB(0,0), 0, 0, STAGE_F(pA1, 128, 49152), )
    PH2(LOADB(1,0),            0, 1, STAGE_F(pB0, 128, 98304), )
    PH2(LOADA(1,0),            1, 1, , )
    PH2(LOADB(0,0),            1, 0, , VM0)
    PH2(LOADA(0,32768) LOADB(0,32768), 0, 0, , )
    PH2(LOADB(1,32768),                0, 1, , )
    PH2(LOADA(1,32768),                1, 1, , )
    PH2(LOADB(0,32768),                1, 0, , )

    // Epilogue: D mapping col = lane&15, row = (lane>>4)*4 + r (m89-verified)
    const int orow0 = bm * 256 + wr * 128;
    const int ocol0 = bn * 256 + wc * 64 + lr;
    const int rsub = (lane >> 4) << 2;
#pragma unroll
    for (int mi = 0; mi < 8; ++mi) {
#pragma unroll
        for (int r = 0; r < 4; ++r) {
            int row = orow0 + mi * 16 + rsub + r;
            float* cp = C + (size_t)row * N_DIM + ocol0;
#pragma unroll
            for (int ni = 0; ni < 4; ++ni)
                cp[ni * 16] = acc[mi][ni][r];
        }
    }
}

// ---------------------------------------------------------------------------
// Fallback GEMM (fp32 A staged with conversion) — only if workspace too small.
// ---------------------------------------------------------------------------
__global__ __launch_bounds__(256) void gemm_fb(const float* __restrict__ A,
                                               const short* __restrict__ B,
                                               float* __restrict__ C) {
    __shared__ short Al[128 * 32];
    __shared__ short Bl[128 * 32];
    const int bid0 = blockIdx.x;
    const int bid = (bid0 & 7) * 512 + (bid0 >> 3);
    const int bm = bid >> 5, bn = bid & 31;
    const int tid = threadIdx.x;
    const int lane = tid & 63;
    const int w = tid >> 6;
    const int wr = w >> 1, wc = w & 1;
    const int lr = lane & 15;
    const int lk = (lane >> 4) << 3;
    float4_t acc[4][4] = {};
    for (int k0 = 0; k0 < K_DIM; k0 += 32) {
        __syncthreads();
#pragma unroll
        for (int i = 0; i < 2; ++i) {
            int e = i * 2048 + tid * 8;
            int row = e >> 5, col = e & 31;
            const float* gp = A + (size_t)(bm * 128 + row) * K_DIM + k0 + col;
            float4 fa = *(const float4*)gp;
            float4 fb = *(const float4*)(gp + 4);
            short8_t v;
            v[0] = f2bf(fa.x); v[1] = f2bf(fa.y); v[2] = f2bf(fa.z); v[3] = f2bf(fa.w);
            v[4] = f2bf(fb.x); v[5] = f2bf(fb.y); v[6] = f2bf(fb.z); v[7] = f2bf(fb.w);
            *(short8_t*)&Al[e] = v;
        }
#pragma unroll
        for (int i = 0; i < 2; ++i) {
            int f = i * 4096 + tid * 16;
            int row = f >> 6, colb = f & 63;
            const char* gb = (const char*)B + ((size_t)(bn * 128 + row) * K_DIM + k0) * 2 + colb;
            __builtin_amdgcn_global_load_lds(
                (const __attribute__((address_space(1))) void*)gb,
                (__attribute__((address_space(3))) void*)((char*)Bl + f), 16, 0, 0);
        }
        __syncthreads();
        short8_t af[4], bf[4];
#pragma unroll
        for (int mi = 0; mi < 4; ++mi)
            af[mi] = *(const short8_t*)&Al[(wr * 64 + mi * 16 + lr) * 32 + lk];
#pragma unroll
        for (int ni = 0; ni < 4; ++ni)
            bf[ni] = *(const short8_t*)&Bl[(wc * 64 + ni * 16 + lr) * 32 + lk];
#pragma unroll
        for (int mi = 0; mi < 4; ++mi)
#pragma unroll
            for (int ni = 0; ni < 4; ++ni)
                acc[mi][ni] = __builtin_amdgcn_mfma_f32_16x16x32_bf16(af[mi], bf[ni], acc[mi][ni], 0, 0, 0);
    }
    const int orow0 = bm * 128 + wr * 64;
    const int ocol0 = bn * 128 + wc * 64 + (lane & 15);
#pragma unroll
    for (int mi = 0; mi < 4; ++mi)
#pragma unroll
        for (int r = 0; r < 4; ++r) {
            int row = orow0 + mi * 16 + ((lane >> 4) << 2) + r;
            float* cp = C + (size_t)row * N_DIM + ocol0;
#pragma unroll
            for (int ni = 0; ni < 4; ++ni)
                cp[ni * 16] = acc[mi][ni][r];
        }
}

// ---------------------------------------------------------------------------
extern "C" void kernel_launch(void* const* d_in, const int* in_sizes, int n_in,
                              void* d_out, int out_size, void* d_ws, size_t ws_size,
                              hipStream_t stream) {
    const float* x     = (const float*)d_in[0];
    const int*   wd    = (const int*)d_in[1];
    const float* scale = (const float*)d_in[2];
    const float* lut   = (const float*)d_in[3];
    float* out = (float*)d_out;

    const size_t wq_bytes = (size_t)N_DIM * K_DIM * 2;   // 32 MB
    const size_t xb_bytes = (size_t)M_DIM * K_DIM * 2;   // 128 MB
    short* Wq = (short*)d_ws;
    short* xb = (short*)((char*)d_ws + wq_bytes);
    const bool have_xb = ws_size >= wq_bytes + xb_bytes;

    dequant_w<<<8192, 256, 0, stream>>>(wd, scale, lut, Wq);

    if (have_xb) {
        conv_x<<<32768, 256, 0, stream>>>(x, xb);
        gemm8<<<(M_DIM / 256) * (N_DIM / 256), 512, 0, stream>>>(xb, Wq, out);
    } else {
        gemm_fb<<<(M_DIM / 128) * (N_DIM / 128), 256, 0, stream>>>(x, Wq, out);
    }
}